// Round 1
// baseline (1532.961 us; speedup 1.0000x reference)
//
#include <hip/hip_runtime.h>
#include <hip/hip_bf16.h>
#include <math.h>

// Problem constants
#define NSEQ 2048
#define TT   128
#define EE   128
#define HH   256
#define GG   1024
#define LL   1000
#define NT   512        // 8 waves
#define NGRP 32         // groups of 64 seqs
#define NMEM 8          // members (blocks) per group; member owns 32 h-units
#define SEQG 64
#define NKT  12         // K-tiles of 32: 4 x + 8 h
#define NMT  64
#define NKT_O 8
#define WSA_ELEMS (NMT * NKT * 64 * 8)      // 768 KB bf16
#define WSO_ELEMS (NMT * NKT_O * 64 * 8)    // 512 KB bf16
// ghf: [grp][member][parity][cg][64 lanes][8 shorts] = 2 MB
#define GHF_SHORTS ((size_t)NGRP * NMEM * 2 * 4 * 64 * 8)
// per-wave flags: [grp][member][wave]
#define NFLAGS (NGRP * NMEM * 8)

typedef __attribute__((ext_vector_type(8))) short bf16x8;
typedef __attribute__((ext_vector_type(4))) float f32x4;
typedef unsigned long long u64;

__device__ __forceinline__ unsigned short f2bf(float f) {
    union { float f; unsigned u; } v; v.f = f;
    unsigned r = v.u + 0x7FFF + ((v.u >> 16) & 1);   // RNE
    return (unsigned short)(r >> 16);
}
__device__ __forceinline__ float sigf(float x) { return 1.0f / (1.0f + __expf(-x)); }
__device__ __forceinline__ float tanh_fast(float x) { return 1.0f - 2.0f / (1.0f + __expf(2.0f * x)); }

// system-scope relaxed 8B ops: sc0+sc1 (served at L3) — NO wbl2/buffer_inv
__device__ __forceinline__ void st8_sys(unsigned short* p, unsigned lo, unsigned hi) {
    u64 v = (u64)lo | ((u64)hi << 32);
    __hip_atomic_store((u64*)p, v, __ATOMIC_RELAXED, __HIP_MEMORY_SCOPE_SYSTEM);
}
__device__ __forceinline__ bf16x8 ld16_sys(const unsigned short* p) {
    u64 lo = __hip_atomic_load((const u64*)p,       __ATOMIC_RELAXED, __HIP_MEMORY_SCOPE_SYSTEM);
    u64 hi = __hip_atomic_load((const u64*)(p + 4), __ATOMIC_RELAXED, __HIP_MEMORY_SCOPE_SYSTEM);
    union { u64 q[2]; bf16x8 v; } u; u.q[0] = lo; u.q[1] = hi;
    return u.v;
}

__global__ void init_out_kernel(float* out, int* flags) {
    int i = blockIdx.x * blockDim.x + threadIdx.x;
    if (i < HH + 1) out[i] = 0.0f;
    if (i < NFLAGS) flags[i] = 0;
}

// Pre-shuffle weights into MFMA A-fragment order, bf16 (layout verified R2-R7).
__global__ void convert_weights(const float* __restrict__ Wih, const float* __restrict__ Whh,
                                const float* __restrict__ Wout,
                                unsigned short* __restrict__ wsA, unsigned short* __restrict__ wsO) {
    int gid = blockIdx.x * blockDim.x + threadIdx.x;
    if (gid < NMT * NKT * 64) {
        int lane = gid & 63, tile = gid >> 6;
        int kt = tile % NKT, mt = tile / NKT;
        int row = mt * 16 + (lane & 15);
        int kb  = kt * 32 + (lane >> 4) * 8;
        unsigned short o[8];
#pragma unroll
        for (int j = 0; j < 8; ++j) {
            int k = kb + j;
            float v = (k < EE) ? Wih[row * EE + k] : Whh[row * HH + (k - EE)];
            o[j] = f2bf(v);
        }
        uint4 pk;
        pk.x = o[0] | ((unsigned)o[1] << 16); pk.y = o[2] | ((unsigned)o[3] << 16);
        pk.z = o[4] | ((unsigned)o[5] << 16); pk.w = o[6] | ((unsigned)o[7] << 16);
        *(uint4*)(wsA + (size_t)gid * 8) = pk;
    } else {
        int g2 = gid - NMT * NKT * 64;
        if (g2 < NMT * NKT_O * 64) {
            int lane = g2 & 63, tile = g2 >> 6;
            int kt = tile % NKT_O, mt = tile / NKT_O;
            int row = mt * 16 + (lane & 15);
            int ub  = kt * 32 + (lane >> 4) * 8;
            unsigned short o[8];
#pragma unroll
            for (int j = 0; j < 8; ++j)
                o[j] = (row < LL) ? f2bf(Wout[row * HH + ub + j]) : (unsigned short)0;
            uint4 pk;
            pk.x = o[0] | ((unsigned)o[1] << 16); pk.y = o[2] | ((unsigned)o[3] << 16);
            pk.z = o[4] | ((unsigned)o[5] << 16); pk.w = o[6] | ((unsigned)o[7] << 16);
            *(uint4*)(wsO + (size_t)g2 * 8) = pk;
        }
    }
}

// Per-wave sync domains: the 4 cg (16-seq) batches never mix, so each wave
// syncs only with the 16 waves (8 members x 2 jj-halves) of its own cg.
// No block barriers in the recurrence; per-wave flags posted after a
// wave-local vmcnt drain; partner frags loaded eagerly as flags arrive.
__launch_bounds__(NT, 2)
__global__ void lstm_group_kernel(
    const int* __restrict__ tokens, const int* __restrict__ lengths,
    const int* __restrict__ labels, const float* __restrict__ emb,
    const float* __restrict__ bih,  const float* __restrict__ bhh,
    const float* __restrict__ bout,
    const unsigned short* __restrict__ wsA, const unsigned short* __restrict__ wsO,
    unsigned short* __restrict__ ghf, int* __restrict__ flags,
    float* __restrict__ out)
{
    __shared__ __align__(16) unsigned short wlds[8 * 12 * 64 * 8];   // 96 KB A-frags
    __shared__ __align__(16) unsigned short xf[8 * 4 * 64 * 8];      // 32 KB per-wave x B-frags
    __shared__ int labv[SEQG];
    __shared__ int mxl[4];           // per-cg maxlen

    const int tid = threadIdx.x;
    const int w   = tid >> 6;
    const int l   = tid & 63;
    const int lq  = l >> 4;
    const int ls  = l & 15;
    const int jj  = w >> 2;        // row half (0/1)
    const int cg  = w & 3;         // col group (16 seqs) == sync domain
    const int grp = blockIdx.x & (NGRP - 1);
    const int m   = blockIdx.x >> 5;
    const int n0  = grp * SEQG;

    int* const flagBase = flags + grp * (NMEM * 8);

    // per-cg maxlen: xor-reduce within 16-lane groups
    int mg = lengths[n0 + l];
#pragma unroll
    for (int s = 1; s < 16; s <<= 1) mg = max(mg, __shfl_xor(mg, s, 64));
    const int maxlen_c = __shfl(mg, cg * 16, 64);
    const int len_s = lengths[n0 + cg * 16 + ls];
    if (w == 0 && ls == 0) mxl[lq] = mg;        // lanes 0,16,32,48 -> groups 0..3
    if (tid < SEQG) labv[tid] = labels[n0 + tid];

    // biases in registers (per-lane gate rows for this wave's acc slots)
    f32x4 biasv[4];
#pragma unroll
    for (int g = 0; g < 4; ++g)
#pragma unroll
        for (int r = 0; r < 4; ++r) {
            int row = 256 * g + 32 * m + 16 * jj + 4 * lq + r;
            biasv[g][r] = bih[row] + bhh[row];
        }

    // ---- one-time: this member's A-frags (8 mt x 12 kt) -> LDS ----
    for (int idx = tid; idx < 8 * 12 * 64; idx += NT) {
        int mtl = idx / 768;
        int rem = idx - mtl * 768;
        int kt = rem >> 6, l2 = rem & 63;
        int g = mtl >> 1, j2 = mtl & 1;
        int gmt = 16 * g + 2 * m + j2;
        *(uint4*)&wlds[(size_t)idx * 8] =
            *(const uint4*)(wsA + ((size_t)(gmt * NKT + kt) * 64 + l2) * 8);
    }
    __syncthreads();   // wlds + labv + mxl visible (only block barrier before epilogue)

    // h publish mapping: unit u = 16*jj + 4*lq + r in member's 32-k tile
    const int u8      = 2 * jj + (lq >> 1);
    const int lanep_h = 16 * u8 + ls;
    const int joff_h  = 4 * (lq & 1);
    const size_t gb0  = ((size_t)((grp * NMEM + m) * 2 + 0) * 4 + cg) * 512 + (size_t)lanep_h * 8 + joff_h;
    const size_t gb1  = gb0 + 4 * 512;

    // zero own h(0) slots (parity 0), wave-local drain, post readiness
    st8_sys(&ghf[gb0], 0u, 0u);
    asm volatile("s_waitcnt vmcnt(0)" ::: "memory");
    if (l == 0)
        __hip_atomic_store(&flagBase[m * 8 + w], 1, __ATOMIC_RELAXED, __HIP_MEMORY_SCOPE_SYSTEM);

    // ---- per-wave x gather/stage: lane (q=lq, ls) owns seq ls, dims [32q,32q+32) ----
    const int q = lq;
    unsigned short* const xfw = xf + (size_t)w * (4 * 64 * 8);
    const int seqi = (n0 + cg * 16 + ls) * TT;

    f32x4 xg[8];
    auto gatherX = [&](int t) {
        int tok = tokens[seqi + t];
        const float* er = emb + (size_t)tok * EE + 32 * q;
#pragma unroll
        for (int j2 = 0; j2 < 8; ++j2) xg[j2] = *(const f32x4*)(er + 4 * j2);
    };
    auto stageX = [&]() {
#pragma unroll
        for (int dcp = 0; dcp < 4; ++dcp) {
            uint4 pk;
            pk.x = f2bf(xg[2*dcp][0])   | ((unsigned)f2bf(xg[2*dcp][1])   << 16);
            pk.y = f2bf(xg[2*dcp][2])   | ((unsigned)f2bf(xg[2*dcp][3])   << 16);
            pk.z = f2bf(xg[2*dcp+1][0]) | ((unsigned)f2bf(xg[2*dcp+1][1]) << 16);
            pk.w = f2bf(xg[2*dcp+1][2]) | ((unsigned)f2bf(xg[2*dcp+1][3]) << 16);
            *(uint4*)&xfw[(size_t)(q * 64 + ls + 16 * dcp) * 8] = pk;
        }
    };

    // x(0) stage + x(1) prefetch
    gatherX(0);
    stageX();
    if (maxlen_c > 1) gatherX(1);

    // acc = bias + xpart(x(0))  (wave-local LDS, no barrier needed)
    f32x4 acc[4], accN[4];
#pragma unroll
    for (int g = 0; g < 4; ++g) acc[g] = biasv[g];
#pragma unroll
    for (int kt = 0; kt < 4; ++kt) {
        const bf16x8 bx = *(const bf16x8*)&xfw[(size_t)(kt * 64 + l) * 8];
#pragma unroll
        for (int g = 0; g < 4; ++g)
            acc[g] = __builtin_amdgcn_mfma_f32_16x16x32_bf16(
                *(const bf16x8*)&wlds[(size_t)(((2 * g + jj) * 12 + kt) * 64 + l) * 8],
                bx, acc[g], 0, 0, 0);
    }

    float c_reg[4], h_reg[4];
#pragma unroll
    for (int r = 0; r < 4; ++r) { c_reg[r] = 0.0f; h_reg[r] = 0.0f; }

    // ---- recurrence: barrier-free, per-wave flags ----
    for (int t = 0; t < maxlen_c; ++t) {
        const int cur = t & 1;
        const bool doX = (t + 1 < maxlen_c);

        if (doX) stageX();                       // x(t+1) -> own LDS region
        if (t + 2 < maxlen_c) gatherX(t + 2);    // in flight under the poll

        // poll the 16 flags of this cg-domain; issue each member's frag load
        // as soon as its wave-pair is ready (overlaps straggler wait w/ fetch)
        bf16x8 bp[8];
        {
            const int need = t + 1;
            unsigned loaded = 0;
            do {
                int fa = 0x7fffffff;
                if (l < 8) {
                    int f0 = __hip_atomic_load(&flagBase[l * 8 + cg],     __ATOMIC_RELAXED, __HIP_MEMORY_SCOPE_SYSTEM);
                    int f1 = __hip_atomic_load(&flagBase[l * 8 + cg + 4], __ATOMIC_RELAXED, __HIP_MEMORY_SCOPE_SYSTEM);
                    fa = min(f0, f1);
                }
                unsigned rm = (unsigned)__ballot(fa >= need) & 0xFFu;   // bit p = member p ready
                unsigned newp = rm & ~loaded;
                if (newp) {
#pragma unroll
                    for (int p = 0; p < 8; ++p)
                        if (newp & (1u << p)) {
                            size_t b = ((size_t)((grp * NMEM + p) * 2 + cur) * 4 + cg) * 512;
                            bp[p] = ld16_sys(&ghf[b + (size_t)l * 8]);
                        }
                    loaded |= newp;
                }
            } while (loaded != 0xFFu);
        }

        // xpart(t+1) into accN — fills the partner-load latency
        if (doX) {
#pragma unroll
            for (int g = 0; g < 4; ++g) accN[g] = biasv[g];
#pragma unroll
            for (int kt = 0; kt < 4; ++kt) {
                const bf16x8 bx = *(const bf16x8*)&xfw[(size_t)(kt * 64 + l) * 8];
#pragma unroll
                for (int g = 0; g < 4; ++g)
                    accN[g] = __builtin_amdgcn_mfma_f32_16x16x32_bf16(
                        *(const bf16x8*)&wlds[(size_t)(((2 * g + jj) * 12 + kt) * 64 + l) * 8],
                        bx, accN[g], 0, 0, 0);
            }
        }

        // h-part (all 8 members incl. self, uniform)
#pragma unroll
        for (int p = 0; p < 8; ++p)
#pragma unroll
            for (int g = 0; g < 4; ++g)
                acc[g] = __builtin_amdgcn_mfma_f32_16x16x32_bf16(
                    *(const bf16x8*)&wlds[(size_t)(((2 * g + jj) * 12 + 4 + p) * 64 + l) * 8],
                    bp[p], acc[g], 0, 0, 0);

        // in-register cell update
        const bool live = (t < len_s);
#pragma unroll
        for (int r = 0; r < 4; ++r) {
            if (live) {
                float ig = sigf(acc[0][r]);
                float fg = sigf(acc[1][r]);
                float gg = tanh_fast(acc[2][r]);
                float og = sigf(acc[3][r]);
                float cc = fg * c_reg[r] + ig * gg;
                c_reg[r] = cc;
                h_reg[r] = og * tanh_fast(cc);
            }
        }

        // publish h(t+1) at parity (t+1)&1; wave-local drain; post own flag
        {
            uint2 hp;
            hp.x = f2bf(h_reg[0]) | ((unsigned)f2bf(h_reg[1]) << 16);
            hp.y = f2bf(h_reg[2]) | ((unsigned)f2bf(h_reg[3]) << 16);
            st8_sys(&ghf[(t & 1) ? gb0 : gb1], hp.x, hp.y);
        }
        asm volatile("s_waitcnt vmcnt(0)" ::: "memory");
        if (l == 0)
            __hip_atomic_store(&flagBase[m * 8 + w], t + 2, __ATOMIC_RELAXED, __HIP_MEMORY_SCOPE_SYSTEM);

        if (doX) {
#pragma unroll
            for (int g = 0; g < 4; ++g) acc[g] = accN[g];
        }
    }

    // ---- epilogue 1: embeds = mean(c_f) for own 32 units ----
#pragma unroll
    for (int r = 0; r < 4; ++r) {
        float v = c_reg[r];
        v += __shfl_xor(v, 1, 64);
        v += __shfl_xor(v, 2, 64);
        v += __shfl_xor(v, 4, 64);
        v += __shfl_xor(v, 8, 64);
        if (ls == 0)
            atomicAdd(&out[32 * m + 16 * jj + 4 * lq + r], v * (1.0f / NSEQ));
    }

    // ---- epilogue 2 (member 0): logits GEMM + log-softmax ----
    if (m == 0) {
        // wait for every wave's final publish (per-domain targets)
        {
            const int p_ = l >> 3, w_ = l & 7;
            const int tgt = mxl[w_ & 3] + 1;
            int d;
            do {
                int f = __hip_atomic_load(&flagBase[p_ * 8 + w_], __ATOMIC_RELAXED, __HIP_MEMORY_SCOPE_SYSTEM);
                d = f - tgt;
#pragma unroll
                for (int s = 1; s < 64; s <<= 1) d = min(d, __shfl_xor(d, s, 64));
                if (d < 0) __builtin_amdgcn_s_sleep(2);
            } while (d < 0);
        }

        float* lg = (float*)wlds;            // reuse: 16 seqs x 1024 logits
        float lossAcc = 0.0f;

        for (int cgo = 0; cgo < 4; ++cgo) {
            const int fin = mxl[cgo] & 1;
            bf16x8 bq[8];
#pragma unroll
            for (int p = 0; p < 8; ++p) {
                size_t b = ((size_t)((grp * NMEM + p) * 2 + fin) * 4 + cgo) * 512;
                bq[p] = ld16_sys(&ghf[b + (size_t)l * 8]);
            }
            __syncthreads();
#pragma unroll
            for (int i = 0; i < 8; ++i) {
                int mt = 8 * w + i;
                f32x4 a = {0.0f, 0.0f, 0.0f, 0.0f};
#pragma unroll
                for (int p = 0; p < 8; ++p)
                    a = __builtin_amdgcn_mfma_f32_16x16x32_bf16(
                        *(const bf16x8*)(wsO + ((size_t)(mt * NKT_O + p) * 64 + l) * 8),
                        bq[p], a, 0, 0, 0);
#pragma unroll
                for (int r = 0; r < 4; ++r) {
                    int cls = 16 * mt + 4 * lq + r;
                    lg[(size_t)ls * 1024 + cls] = (cls < LL) ? (a[r] + bout[cls]) : -INFINITY;
                }
            }
            __syncthreads();
            const int s2 = tid >> 5;
            const int i2 = tid & 31;
            const float* row = &lg[(size_t)s2 * 1024];
            float mx = -INFINITY;
#pragma unroll
            for (int k = 0; k < 32; ++k) mx = fmaxf(mx, row[i2 + 32 * k]);
            mx = fmaxf(mx, __shfl_xor(mx, 1, 64));
            mx = fmaxf(mx, __shfl_xor(mx, 2, 64));
            mx = fmaxf(mx, __shfl_xor(mx, 4, 64));
            mx = fmaxf(mx, __shfl_xor(mx, 8, 64));
            mx = fmaxf(mx, __shfl_xor(mx, 16, 64));
            float sm = 0.0f;
#pragma unroll
            for (int k = 0; k < 32; ++k) sm += __expf(row[i2 + 32 * k] - mx);
            sm += __shfl_xor(sm, 1, 64);
            sm += __shfl_xor(sm, 2, 64);
            sm += __shfl_xor(sm, 4, 64);
            sm += __shfl_xor(sm, 8, 64);
            sm += __shfl_xor(sm, 16, 64);
            if (i2 == 0) {
                int lab = labv[cgo * 16 + s2];
                float lp = row[lab] - mx - __logf(sm);
                lossAcc += -lp;
            }
        }
        if ((tid & 31) == 0)
            atomicAdd(&out[HH], lossAcc * (1.0f / NSEQ));
    }
}

extern "C" void kernel_launch(void* const* d_in, const int* in_sizes, int n_in,
                              void* d_out, int out_size, void* d_ws, size_t ws_size,
                              hipStream_t stream)
{
    const int*   tokens  = (const int*)d_in[0];
    const int*   lengths = (const int*)d_in[1];
    const int*   labels  = (const int*)d_in[2];
    const float* emb     = (const float*)d_in[3];
    const float* Wih     = (const float*)d_in[4];
    const float* Whh     = (const float*)d_in[5];
    const float* bih     = (const float*)d_in[6];
    const float* bhh     = (const float*)d_in[7];
    const float* Wout    = (const float*)d_in[8];
    const float* bout    = (const float*)d_in[9];
    float* out = (float*)d_out;

    unsigned short* wsA  = (unsigned short*)d_ws;
    unsigned short* wsO  = wsA + WSA_ELEMS;
    unsigned short* ghf  = wsO + WSO_ELEMS;
    int*            flg  = (int*)(ghf + GHF_SHORTS);

    hipLaunchKernelGGL(init_out_kernel, dim3(4), dim3(512), 0, stream, out, flg);
    {
        int nthr = NMT * NKT * 64 + NMT * NKT_O * 64;
        hipLaunchKernelGGL(convert_weights, dim3((nthr + 255) / 256), dim3(256), 0, stream,
                           Wih, Whh, Wout, wsA, wsO);
    }
    hipLaunchKernelGGL(lstm_group_kernel, dim3(NGRP * NMEM), dim3(NT), 0, stream,
                       tokens, lengths, labels, emb, bih, bhh, bout, wsA, wsO, ghf, flg, out);
}

// Round 2
// 737.713 us; speedup vs baseline: 2.0780x; 2.0780x over previous
//
#include <hip/hip_runtime.h>
#include <hip/hip_bf16.h>
#include <math.h>

// Problem constants
#define NSEQ 2048
#define TT   128
#define EE   128
#define HH   256
#define GG   1024
#define LL   1000
#define NT   512        // 8 waves
#define NGRP 32         // groups of 64 seqs
#define NMEM 8          // members (blocks) per group; member owns 32 h-units
#define SEQG 64
#define NKT  12         // K-tiles of 32: 4 x + 8 h
#define NMT  64
#define NKT_O 8
#define WSA_ELEMS (NMT * NKT * 64 * 8)      // 768 KB bf16
#define WSO_ELEMS (NMT * NKT_O * 64 * 8)    // 512 KB bf16
// ghf: [grp][member][parity][cg][64 lanes][8 shorts] = 2 MB
#define GHF_SHORTS ((size_t)NGRP * NMEM * 2 * 4 * 64 * 8)
// flags: [grp][member] sync flags, then [grp][member] xcd ids
#define XCD_OFF (NGRP * NMEM)

typedef __attribute__((ext_vector_type(8))) short bf16x8;
typedef __attribute__((ext_vector_type(4))) float f32x4;
typedef unsigned long long u64;

__device__ __forceinline__ unsigned short f2bf(float f) {
    union { float f; unsigned u; } v; v.f = f;
    unsigned r = v.u + 0x7FFF + ((v.u >> 16) & 1);   // RNE
    return (unsigned short)(r >> 16);
}
__device__ __forceinline__ float sigf(float x) { return 1.0f / (1.0f + __expf(-x)); }
__device__ __forceinline__ float tanh_fast(float x) { return 1.0f - 2.0f / (1.0f + __expf(2.0f * x)); }

// Dual-scope 8B/16B ops.
// fast=true  -> AGENT scope (sc0 only): served in the XCD-local L2 (~200cy).
//               Only legal when all 8 group members verified on the same XCD.
// fast=false -> SYSTEM scope (sc0+sc1): fabric/L3-served (~700-900cy), always safe.
__device__ __forceinline__ void st8(unsigned short* p, unsigned lo, unsigned hi, bool fast) {
    u64 v = (u64)lo | ((u64)hi << 32);
    if (fast) __hip_atomic_store((u64*)p, v, __ATOMIC_RELAXED, __HIP_MEMORY_SCOPE_AGENT);
    else      __hip_atomic_store((u64*)p, v, __ATOMIC_RELAXED, __HIP_MEMORY_SCOPE_SYSTEM);
}
__device__ __forceinline__ bf16x8 ld16(const unsigned short* p, bool fast) {
    u64 lo, hi;
    if (fast) {
        lo = __hip_atomic_load((const u64*)p,       __ATOMIC_RELAXED, __HIP_MEMORY_SCOPE_AGENT);
        hi = __hip_atomic_load((const u64*)(p + 4), __ATOMIC_RELAXED, __HIP_MEMORY_SCOPE_AGENT);
    } else {
        lo = __hip_atomic_load((const u64*)p,       __ATOMIC_RELAXED, __HIP_MEMORY_SCOPE_SYSTEM);
        hi = __hip_atomic_load((const u64*)(p + 4), __ATOMIC_RELAXED, __HIP_MEMORY_SCOPE_SYSTEM);
    }
    union { u64 q[2]; bf16x8 v; } u; u.q[0] = lo; u.q[1] = hi;
    return u.v;
}
__device__ __forceinline__ int ld_flag(const int* p, bool fast) {
    if (fast) return __hip_atomic_load(p, __ATOMIC_RELAXED, __HIP_MEMORY_SCOPE_AGENT);
    return __hip_atomic_load(p, __ATOMIC_RELAXED, __HIP_MEMORY_SCOPE_SYSTEM);
}
__device__ __forceinline__ void st_flag(int* p, int v, bool fast) {
    if (fast) __hip_atomic_store(p, v, __ATOMIC_RELAXED, __HIP_MEMORY_SCOPE_AGENT);
    else      __hip_atomic_store(p, v, __ATOMIC_RELAXED, __HIP_MEMORY_SCOPE_SYSTEM);
}

__global__ void init_out_kernel(float* out, int* flags) {
    int i = blockIdx.x * blockDim.x + threadIdx.x;
    if (i < HH + 1) out[i] = 0.0f;
    if (i < 2 * NGRP * NMEM) flags[i] = 0;   // sync flags + xcd ids
}

// Pre-shuffle weights into MFMA A-fragment order, bf16 (layout verified R2-R7).
__global__ void convert_weights(const float* __restrict__ Wih, const float* __restrict__ Whh,
                                const float* __restrict__ Wout,
                                unsigned short* __restrict__ wsA, unsigned short* __restrict__ wsO) {
    int gid = blockIdx.x * blockDim.x + threadIdx.x;
    if (gid < NMT * NKT * 64) {
        int lane = gid & 63, tile = gid >> 6;
        int kt = tile % NKT, mt = tile / NKT;
        int row = mt * 16 + (lane & 15);
        int kb  = kt * 32 + (lane >> 4) * 8;
        unsigned short o[8];
#pragma unroll
        for (int j = 0; j < 8; ++j) {
            int k = kb + j;
            float v = (k < EE) ? Wih[row * EE + k] : Whh[row * HH + (k - EE)];
            o[j] = f2bf(v);
        }
        uint4 pk;
        pk.x = o[0] | ((unsigned)o[1] << 16); pk.y = o[2] | ((unsigned)o[3] << 16);
        pk.z = o[4] | ((unsigned)o[5] << 16); pk.w = o[6] | ((unsigned)o[7] << 16);
        *(uint4*)(wsA + (size_t)gid * 8) = pk;
    } else {
        int g2 = gid - NMT * NKT * 64;
        if (g2 < NMT * NKT_O * 64) {
            int lane = g2 & 63, tile = g2 >> 6;
            int kt = tile % NKT_O, mt = tile / NKT_O;
            int row = mt * 16 + (lane & 15);
            int ub  = kt * 32 + (lane >> 4) * 8;
            unsigned short o[8];
#pragma unroll
            for (int j = 0; j < 8; ++j)
                o[j] = (row < LL) ? f2bf(Wout[row * HH + ub + j]) : (unsigned short)0;
            uint4 pk;
            pk.x = o[0] | ((unsigned)o[1] << 16); pk.y = o[2] | ((unsigned)o[3] << 16);
            pk.z = o[4] | ((unsigned)o[5] << 16); pk.w = o[6] | ((unsigned)o[7] << 16);
            *(uint4*)(wsO + (size_t)g2 * 8) = pk;
        }
    }
}

// 8-way split LSTM, software-pipelined (R0 structure) + runtime-verified
// XCD co-location fast path: group members are blockIdx = 32*m + grp, which
// round-robins to XCD (grp % 8) -> all 8 members share one XCD's L2. If the
// runtime handshake confirms this, all ghf/flag traffic switches from
// SYSTEM scope (fabric-served) to AGENT scope (XCD-L2-served).
__launch_bounds__(NT, 2)
__global__ void lstm_group_kernel(
    const int* __restrict__ tokens, const int* __restrict__ lengths,
    const int* __restrict__ labels, const float* __restrict__ emb,
    const float* __restrict__ bih,  const float* __restrict__ bhh,
    const float* __restrict__ bout,
    const unsigned short* __restrict__ wsA, const unsigned short* __restrict__ wsO,
    unsigned short* __restrict__ ghf, int* __restrict__ flags,
    float* __restrict__ out)
{
    __shared__ __align__(16) unsigned short wlds[8 * 12 * 64 * 8];   // 96 KB A-frags
    __shared__ __align__(16) unsigned short xfS[4 * 4 * 64 * 8];     // 16 KB x B-frags (single)
    __shared__ __align__(16) unsigned short hf[2 * 4 * 64 * 8];      // 8 KB own-h B-frags (dbuf)
    __shared__ int   labv[SEQG];
    __shared__ int   ready_s;

    const int tid = threadIdx.x;
    const int w   = tid >> 6;
    const int l   = tid & 63;
    const int lq  = l >> 4;
    const int ls  = l & 15;
    const int jj  = w >> 2;        // row half (0/1)
    const int cg  = w & 3;         // col group (16 seqs)
    const int grp = blockIdx.x & (NGRP - 1);
    const int m   = blockIdx.x >> 5;
    const int n0  = grp * SEQG;

    int* const flagBase = flags + grp * NMEM;
    int* const xcdBase  = flags + XCD_OFF + grp * NMEM;

    int maxlen = lengths[n0 + l];
#pragma unroll
    for (int s = 1; s < 64; s <<= 1) maxlen = max(maxlen, __shfl_xor(maxlen, s, 64));
    const int len_s = lengths[n0 + cg * 16 + ls];

    if (tid < SEQG) labv[tid] = labels[n0 + tid];
    if (tid == 0) ready_s = 0;

    // biases in registers (per-lane: gate rows for this wave's acc slots)
    f32x4 biasv[4];
#pragma unroll
    for (int g = 0; g < 4; ++g)
#pragma unroll
        for (int r = 0; r < 4; ++r) {
            int row = 256 * g + 32 * m + 16 * jj + 4 * lq + r;
            biasv[g][r] = bih[row] + bhh[row];
        }

    // ---- one-time: this member's A-frags (8 mt x 12 kt) -> LDS ----
    for (int idx = tid; idx < 8 * 12 * 64; idx += NT) {
        int mtl = idx / 768;
        int rem = idx - mtl * 768;
        int kt = rem >> 6, l2 = rem & 63;
        int g = mtl >> 1, j2 = mtl & 1;
        int gmt = 16 * g + 2 * m + j2;
        *(uint4*)&wlds[(size_t)idx * 8] =
            *(const uint4*)(wsA + ((size_t)(gmt * NKT + kt) * 64 + l2) * 8);
    }

    // publish this member's XCD id (guarded by the flag=1 handshake below)
    {
        unsigned xcc;
        asm volatile("s_getreg_b32 %0, hwreg(HW_REG_XCC_ID)" : "=s"(xcc));
        if (tid == 0)
            __hip_atomic_store(&xcdBase[m], (int)(xcc + 1),
                               __ATOMIC_RELAXED, __HIP_MEMORY_SCOPE_SYSTEM);
    }

    // zero hf buf0 + ghf parity0 slice (h(0) = 0) — SYSTEM (pre-decision)
    if (tid < 256) {
        uint4 z = {0, 0, 0, 0};
        *(uint4*)&hf[(size_t)tid * 8] = z;
        size_t base = ((size_t)((grp * NMEM + m) * 2 + 0) * 4) * 512 + (size_t)tid * 8;
        st8(&ghf[base], 0, 0, false);
        st8(&ghf[base + 4], 0, 0, false);
    }

    // x staging map: thread -> (seq, 16-dim octet)
    const int xs_s   = tid & 63;
    const int xs_oct = tid >> 6;

    auto stageX = [&](const f32x4* xv) {
#pragma unroll
        for (int dc = 0; dc < 4; ++dc) {
            int d0 = 16 * xs_oct + 4 * dc;
            int kt = d0 >> 5, cgs = xs_s >> 4;
            int lanep = (xs_s & 15) + 16 * ((d0 >> 3) & 3);
            uint2 pk;
            pk.x = f2bf(xv[dc][0]) | ((unsigned)f2bf(xv[dc][1]) << 16);
            pk.y = f2bf(xv[dc][2]) | ((unsigned)f2bf(xv[dc][3]) << 16);
            *(uint2*)&xfS[(size_t)((kt * 4 + cgs) * 64 + lanep) * 8 + (d0 & 4)] = pk;
        }
    };

    // stage x(0)
    {
        int tok = tokens[(n0 + xs_s) * TT + 0];
        const float* er = emb + (size_t)tok * EE + 16 * xs_oct;
        f32x4 x0[4];
#pragma unroll
        for (int dc = 0; dc < 4; ++dc) x0[dc] = *(const f32x4*)(er + 4 * dc);
        stageX(x0);
    }
    __syncthreads();   // drains ghf zero stores + xcd store + x(0) staging + wlds
    if (tid == 0)
        __hip_atomic_store(&flagBase[m], 1, __ATOMIC_RELAXED, __HIP_MEMORY_SCOPE_SYSTEM);

    // relay wait: wave0 polls flags; other waves spin on LDS
    auto relay_wait = [&](int need, bool fastm) {
        if (w == 0) {
            int f;
            do {
                f = 0x7fffffff;
                if (l < NMEM)
                    f = ld_flag(&flagBase[l], fastm);
                f = min(f, __shfl_xor(f, 1, 64));
                f = min(f, __shfl_xor(f, 2, 64));
                f = min(f, __shfl_xor(f, 4, 64));
                f = __shfl(f, 0, 64);
                if (f < need) __builtin_amdgcn_s_sleep(2);
            } while (f < need);
            __hip_atomic_store(&ready_s, need, __ATOMIC_RELEASE, __HIP_MEMORY_SCOPE_WORKGROUP);
        } else {
            while (__hip_atomic_load(&ready_s, __ATOMIC_ACQUIRE, __HIP_MEMORY_SCOPE_WORKGROUP) < need)
                __builtin_amdgcn_s_sleep(1);
        }
    };

    // ---- scope decision: all 8 members on one XCD? ----
    relay_wait(1, false);
    bool fast;
    {
        int x = (l < NMEM)
            ? __hip_atomic_load(&xcdBase[l], __ATOMIC_RELAXED, __HIP_MEMORY_SCOPE_SYSTEM) : 0;
        int x0 = __shfl(x, 0, 64);
        bool eq = (l >= NMEM) || (x == x0 && x != 0);
        fast = (__ballot(eq) == ~0ull);
    }

    // prefetch x(1)
    f32x4 xv[4];
    if (maxlen > 1) {
        int tok = tokens[(n0 + xs_s) * TT + 1];
        const float* er = emb + (size_t)tok * EE + 16 * xs_oct;
#pragma unroll
        for (int dc = 0; dc < 4; ++dc) xv[dc] = *(const f32x4*)(er + 4 * dc);
    }

    // acc = bias + xpart(x(0))
    f32x4 acc[4], accN[4];
#pragma unroll
    for (int g = 0; g < 4; ++g) acc[g] = biasv[g];
#pragma unroll
    for (int kt = 0; kt < 4; ++kt) {
        const bf16x8 bx = *(const bf16x8*)&xfS[(size_t)((kt * 4 + cg) * 64 + l) * 8];
#pragma unroll
        for (int g = 0; g < 4; ++g)
            acc[g] = __builtin_amdgcn_mfma_f32_16x16x32_bf16(
                *(const bf16x8*)&wlds[(size_t)(((2 * g + jj) * 12 + kt) * 64 + l) * 8],
                bx, acc[g], 0, 0, 0);
    }
    __syncthreads();   // xfS reads done; iter 0 may restage

    float c_reg[4], h_reg[4];
#pragma unroll
    for (int r = 0; r < 4; ++r) { c_reg[r] = 0.0f; h_reg[r] = 0.0f; }

    // h publish mapping: unit u = 16*jj + 4*lq + r in member's 32-k tile
    const int u8      = 2 * jj + (lq >> 1);
    const int lanep_h = 16 * u8 + ls;
    const int joff_h  = 4 * (lq & 1);
    const size_t gb0  = ((size_t)((grp * NMEM + m) * 2 + 0) * 4 + cg) * 512 + (size_t)lanep_h * 8 + joff_h;
    const size_t gb1  = gb0 + 4 * 512;

    // ---- recurrence (steady state: xpart(t) already in acc) ----
    for (int t = 0; t < maxlen; ++t) {
        const int cur = t & 1, nxt = cur ^ 1;
        const bool doX = (t + 1 < maxlen);

        // head: stage x(t+1) from regs (partner-independent)
        if (doX) stageX(xv);
        // own-h B-frag (hf[cur] written before last barrier)
        const bf16x8 bo = *(const bf16x8*)&hf[(size_t)((cur * 4 + cg) * 64 + l) * 8];
        if (doX) __syncthreads();   // staging visible; cheap (no vmem pending)

        // prefetch x(t+2) (drained at barrier B, a full iter away)
        if (t + 2 < maxlen) {
            int tok = tokens[(n0 + xs_s) * TT + t + 2];
            const float* er = emb + (size_t)tok * EE + 16 * xs_oct;
#pragma unroll
            for (int dc = 0; dc < 4; ++dc) xv[dc] = *(const f32x4*)(er + 4 * dc);
        }

        // xpart(t+1) into accN — fills the wait window
        if (doX) {
#pragma unroll
            for (int g = 0; g < 4; ++g) accN[g] = biasv[g];
#pragma unroll
            for (int kt = 0; kt < 4; ++kt) {
                const bf16x8 bx = *(const bf16x8*)&xfS[(size_t)((kt * 4 + cg) * 64 + l) * 8];
#pragma unroll
                for (int g = 0; g < 4; ++g)
                    accN[g] = __builtin_amdgcn_mfma_f32_16x16x32_bf16(
                        *(const bf16x8*)&wlds[(size_t)(((2 * g + jj) * 12 + kt) * 64 + l) * 8],
                        bx, accN[g], 0, 0, 0);
            }
        }

        // wait for all members' h(t)
        relay_wait(t + 1, fast);

        // partner B-frag loads (XCD-L2 in fast mode)
        bf16x8 bp[7];
#pragma unroll
        for (int i = 0; i < 7; ++i) {
            int p = i + (i >= m ? 1 : 0);
            size_t b = ((size_t)((grp * NMEM + p) * 2 + cur) * 4 + cg) * 512;
            bp[i] = ld16(&ghf[b + (size_t)l * 8], fast);
        }

        // own-h part first (hides partner-load latency)
#pragma unroll
        for (int g = 0; g < 4; ++g)
            acc[g] = __builtin_amdgcn_mfma_f32_16x16x32_bf16(
                *(const bf16x8*)&wlds[(size_t)(((2 * g + jj) * 12 + 4 + m) * 64 + l) * 8],
                bo, acc[g], 0, 0, 0);
        // partner-h parts
#pragma unroll
        for (int i = 0; i < 7; ++i) {
            int p = i + (i >= m ? 1 : 0);
            int kt = 4 + p;
#pragma unroll
            for (int g = 0; g < 4; ++g)
                acc[g] = __builtin_amdgcn_mfma_f32_16x16x32_bf16(
                    *(const bf16x8*)&wlds[(size_t)(((2 * g + jj) * 12 + kt) * 64 + l) * 8],
                    bp[i], acc[g], 0, 0, 0);
        }

        // in-register cell update
        const bool live = (t < len_s);
#pragma unroll
        for (int r = 0; r < 4; ++r) {
            if (live) {
                float ig = sigf(acc[0][r]);
                float fg = sigf(acc[1][r]);
                float gg = tanh_fast(acc[2][r]);
                float og = sigf(acc[3][r]);
                float cc = fg * c_reg[r] + ig * gg;
                c_reg[r] = cc;
                h_reg[r] = og * tanh_fast(cc);
            }
        }

        // carry pipelined xpart
        if (doX) {
#pragma unroll
            for (int g = 0; g < 4; ++g) acc[g] = accN[g];
        }

        // publish h(t+1): LDS nxt + ghf store, parity (t+1)&1
        {
            uint2 hp;
            hp.x = f2bf(h_reg[0]) | ((unsigned)f2bf(h_reg[1]) << 16);
            hp.y = f2bf(h_reg[2]) | ((unsigned)f2bf(h_reg[3]) << 16);
            *(uint2*)&hf[(size_t)((nxt * 4 + cg) * 64 + lanep_h) * 8 + joff_h] = hp;
            st8(&ghf[((t + 1) & 1) ? gb1 : gb0], hp.x, hp.y, fast);
        }

        __syncthreads();   // barrier B: drains ghf stores (+ x prefetch loads)
        if (tid == 0)
            st_flag(&flagBase[m], t + 2, fast);
    }

    // ---- epilogue 1: embeds = mean(c_f) for own 32 units ----
#pragma unroll
    for (int r = 0; r < 4; ++r) {
        float v = c_reg[r];
        v += __shfl_xor(v, 1, 64);
        v += __shfl_xor(v, 2, 64);
        v += __shfl_xor(v, 4, 64);
        v += __shfl_xor(v, 8, 64);
        if (ls == 0)
            atomicAdd(&out[32 * m + 16 * jj + 4 * lq + r], v * (1.0f / NSEQ));
    }

    // ---- epilogue 2 (member 0): logits GEMM + log-softmax ----
    if (m == 0) {
        relay_wait(maxlen + 1, fast);
        const int fin = maxlen & 1;
        float* lg = (float*)wlds;            // reuse: 16 seqs x 1024 logits
        float lossAcc = 0.0f;

        for (int cgo = 0; cgo < 4; ++cgo) {
            bf16x8 bq[8];
#pragma unroll
            for (int p = 0; p < 8; ++p) {
                size_t b = ((size_t)((grp * NMEM + p) * 2 + fin) * 4 + cgo) * 512;
                bq[p] = ld16(&ghf[b + (size_t)l * 8], fast);
            }
            __syncthreads();
#pragma unroll
            for (int i = 0; i < 8; ++i) {
                int mt = 8 * w + i;
                f32x4 a = {0.0f, 0.0f, 0.0f, 0.0f};
#pragma unroll
                for (int p = 0; p < 8; ++p)
                    a = __builtin_amdgcn_mfma_f32_16x16x32_bf16(
                        *(const bf16x8*)(wsO + ((size_t)(mt * NKT_O + p) * 64 + l) * 8),
                        bq[p], a, 0, 0, 0);
#pragma unroll
                for (int r = 0; r < 4; ++r) {
                    int cls = 16 * mt + 4 * lq + r;
                    lg[(size_t)ls * 1024 + cls] = (cls < LL) ? (a[r] + bout[cls]) : -INFINITY;
                }
            }
            __syncthreads();
            const int s2 = tid >> 5;
            const int i2 = tid & 31;
            const float* row = &lg[(size_t)s2 * 1024];
            float mx = -INFINITY;
#pragma unroll
            for (int k = 0; k < 32; ++k) mx = fmaxf(mx, row[i2 + 32 * k]);
            mx = fmaxf(mx, __shfl_xor(mx, 1, 64));
            mx = fmaxf(mx, __shfl_xor(mx, 2, 64));
            mx = fmaxf(mx, __shfl_xor(mx, 4, 64));
            mx = fmaxf(mx, __shfl_xor(mx, 8, 64));
            mx = fmaxf(mx, __shfl_xor(mx, 16, 64));
            float sm = 0.0f;
#pragma unroll
            for (int k = 0; k < 32; ++k) sm += __expf(row[i2 + 32 * k] - mx);
            sm += __shfl_xor(sm, 1, 64);
            sm += __shfl_xor(sm, 2, 64);
            sm += __shfl_xor(sm, 4, 64);
            sm += __shfl_xor(sm, 8, 64);
            sm += __shfl_xor(sm, 16, 64);
            if (i2 == 0) {
                int lab = labv[cgo * 16 + s2];
                float lp = row[lab] - mx - __logf(sm);
                lossAcc += -lp;
            }
        }
        if ((tid & 31) == 0)
            atomicAdd(&out[HH], lossAcc * (1.0f / NSEQ));
    }
}

extern "C" void kernel_launch(void* const* d_in, const int* in_sizes, int n_in,
                              void* d_out, int out_size, void* d_ws, size_t ws_size,
                              hipStream_t stream)
{
    const int*   tokens  = (const int*)d_in[0];
    const int*   lengths = (const int*)d_in[1];
    const int*   labels  = (const int*)d_in[2];
    const float* emb     = (const float*)d_in[3];
    const float* Wih     = (const float*)d_in[4];
    const float* Whh     = (const float*)d_in[5];
    const float* bih     = (const float*)d_in[6];
    const float* bhh     = (const float*)d_in[7];
    const float* Wout    = (const float*)d_in[8];
    const float* bout    = (const float*)d_in[9];
    float* out = (float*)d_out;

    unsigned short* wsA  = (unsigned short*)d_ws;
    unsigned short* wsO  = wsA + WSA_ELEMS;
    unsigned short* ghf  = wsO + WSO_ELEMS;
    int*            flg  = (int*)(ghf + GHF_SHORTS);

    hipLaunchKernelGGL(init_out_kernel, dim3(1), dim3(512), 0, stream, out, flg);
    {
        int nthr = NMT * NKT * 64 + NMT * NKT_O * 64;
        hipLaunchKernelGGL(convert_weights, dim3((nthr + 255) / 256), dim3(256), 0, stream,
                           Wih, Whh, Wout, wsA, wsO);
    }
    hipLaunchKernelGGL(lstm_group_kernel, dim3(NGRP * NMEM), dim3(NT), 0, stream,
                       tokens, lengths, labels, emb, bih, bhh, bout, wsA, wsO, ghf, flg, out);
}

// Round 4
// 727.392 us; speedup vs baseline: 2.1075x; 1.0142x over previous
//
#include <hip/hip_runtime.h>
#include <hip/hip_bf16.h>
#include <math.h>

// Problem constants
#define NSEQ 2048
#define TT   128
#define EE   128
#define HH   256
#define GG   1024
#define LL   1000
#define NT   512        // 8 waves
#define NGRP 32         // groups of 64 seqs
#define NMEM 8          // members (blocks) per group; member owns 32 h-units
#define SEQG 64
#define NKT  12         // K-tiles of 32: 4 x + 8 h
#define NMT  64
#define NKT_O 8
#define WSA_ELEMS (NMT * NKT * 64 * 8)      // 768 KB bf16
#define WSO_ELEMS (NMT * NKT_O * 64 * 8)    // 512 KB bf16
// ghf: [grp][member][parity][cg][64 lanes][8 shorts] = 2 MB
// group slice = 64 KB, 1 KB-aligned -> no cache line spans two groups.
#define GHF_SHORTS ((size_t)NGRP * NMEM * 2 * 4 * 64 * 8)
// flags: ONE 128B line per group (8 used ints + 24 pad) -> no line is shared
// by two groups (groups map to different XCDs; false sharing deadlocked R3).
#define FLG_STRIDE 32
#define XCD_OFF (NGRP * FLG_STRIDE)
#define NFLAGW  (2 * NGRP * FLG_STRIDE)     // 2048 ints total

typedef __attribute__((ext_vector_type(8))) short bf16x8;
typedef __attribute__((ext_vector_type(4))) float f32x4;
typedef __attribute__((ext_vector_type(4))) unsigned int u32x4;
typedef unsigned long long u64;

__device__ __forceinline__ unsigned short f2bf(float f) {
    union { float f; unsigned u; } v; v.f = f;
    unsigned r = v.u + 0x7FFF + ((v.u >> 16) & 1);   // RNE
    return (unsigned short)(r >> 16);
}
__device__ __forceinline__ float sigf(float x) { return 1.0f / (1.0f + __expf(-x)); }
__device__ __forceinline__ float tanh_fast(float x) { return 1.0f - 2.0f / (1.0f + __expf(2.0f * x)); }

// ---- SLOW path (always correct): system-scope relaxed, fabric/L3-served ----
__device__ __forceinline__ void st8_sys(unsigned short* p, unsigned lo, unsigned hi) {
    u64 v = (u64)lo | ((u64)hi << 32);
    __hip_atomic_store((u64*)p, v, __ATOMIC_RELAXED, __HIP_MEMORY_SCOPE_SYSTEM);
}
__device__ __forceinline__ bf16x8 ld16_sys(const unsigned short* p) {
    u64 lo = __hip_atomic_load((const u64*)p,       __ATOMIC_RELAXED, __HIP_MEMORY_SCOPE_SYSTEM);
    u64 hi = __hip_atomic_load((const u64*)(p + 4), __ATOMIC_RELAXED, __HIP_MEMORY_SCOPE_SYSTEM);
    union { u64 q[2]; bf16x8 v; } u; u.q[0] = lo; u.q[1] = hi;
    return u.v;
}

// ---- FAST path (same-XCD verified): plain store -> dirty in the XCD L2
// (vL1 is write-through; L2 is the intra-XCD coherence point); sc0 load
// bypasses L1, served by that same L2. PROTOCOL PURITY: any line touched by
// these helpers is NEVER touched by SYSTEM ops within this launch (mixing
// strands clean stale lines in L2 -> deadlock; R3 post-mortem). ----
__device__ __forceinline__ void st8_f(unsigned short* p, unsigned lo, unsigned hi) {
    u64 v = (u64)lo | ((u64)hi << 32);
    asm volatile("global_store_dwordx2 %0, %1, off" :: "v"(p), "v"(v) : "memory");
}
__device__ __forceinline__ void stflag_f(int* p, int v) {
    asm volatile("global_store_dword %0, %1, off" :: "v"(p), "v"(v) : "memory");
}
__device__ __forceinline__ int ldflag_f(const int* p) {
    int r;
    asm volatile("global_load_dword %0, %1, off sc0\n\t"
                 "s_waitcnt vmcnt(0)" : "=v"(r) : "v"(p) : "memory");
    return r;
}
__device__ __forceinline__ bf16x8 ld16_f(const unsigned short* p) {
    union { u32x4 q; bf16x8 v; } u;
    asm volatile("global_load_dwordx4 %0, %1, off sc0\n\t"
                 "s_waitcnt vmcnt(0)" : "=v"(u.q) : "v"(p) : "memory");
    return u.v;
}

__global__ void init_out_kernel(float* out, int* flags) {
    int i = blockIdx.x * blockDim.x + threadIdx.x;
    if (i < HH + 1) out[i] = 0.0f;
    if (i < NFLAGW) flags[i] = 0;   // sync flags + xcd ids (padded)
}

// Pre-shuffle weights into MFMA A-fragment order, bf16 (layout verified R2-R7).
__global__ void convert_weights(const float* __restrict__ Wih, const float* __restrict__ Whh,
                                const float* __restrict__ Wout,
                                unsigned short* __restrict__ wsA, unsigned short* __restrict__ wsO) {
    int gid = blockIdx.x * blockDim.x + threadIdx.x;
    if (gid < NMT * NKT * 64) {
        int lane = gid & 63, tile = gid >> 6;
        int kt = tile % NKT, mt = tile / NKT;
        int row = mt * 16 + (lane & 15);
        int kb  = kt * 32 + (lane >> 4) * 8;
        unsigned short o[8];
#pragma unroll
        for (int j = 0; j < 8; ++j) {
            int k = kb + j;
            float v = (k < EE) ? Wih[row * EE + k] : Whh[row * HH + (k - EE)];
            o[j] = f2bf(v);
        }
        uint4 pk;
        pk.x = o[0] | ((unsigned)o[1] << 16); pk.y = o[2] | ((unsigned)o[3] << 16);
        pk.z = o[4] | ((unsigned)o[5] << 16); pk.w = o[6] | ((unsigned)o[7] << 16);
        *(uint4*)(wsA + (size_t)gid * 8) = pk;
    } else {
        int g2 = gid - NMT * NKT * 64;
        if (g2 < NMT * NKT_O * 64) {
            int lane = g2 & 63, tile = g2 >> 6;
            int kt = tile % NKT_O, mt = tile / NKT_O;
            int row = mt * 16 + (lane & 15);
            int ub  = kt * 32 + (lane >> 4) * 8;
            unsigned short o[8];
#pragma unroll
            for (int j = 0; j < 8; ++j)
                o[j] = (row < LL) ? f2bf(Wout[row * HH + ub + j]) : (unsigned short)0;
            uint4 pk;
            pk.x = o[0] | ((unsigned)o[1] << 16); pk.y = o[2] | ((unsigned)o[3] << 16);
            pk.z = o[4] | ((unsigned)o[5] << 16); pk.w = o[6] | ((unsigned)o[7] << 16);
            *(uint4*)(wsO + (size_t)g2 * 8) = pk;
        }
    }
}

// 8-way split LSTM (R0 structure) + runtime-verified XCD co-location fast
// path. Order of operations guarantees protocol purity: the mode decision
// (SYSTEM-only xcd-id handshake, own padded lines) completes BEFORE any
// store to flag/ghf lines; afterwards every flag/ghf access in the launch
// uses exactly one protocol (verdict is unanimous across the group since all
// members derive it from the same stable id values).
__launch_bounds__(NT, 2)
__global__ void lstm_group_kernel(
    const int* __restrict__ tokens, const int* __restrict__ lengths,
    const int* __restrict__ labels, const float* __restrict__ emb,
    const float* __restrict__ bih,  const float* __restrict__ bhh,
    const float* __restrict__ bout,
    const unsigned short* __restrict__ wsA, const unsigned short* __restrict__ wsO,
    unsigned short* __restrict__ ghf, int* __restrict__ flags,
    float* __restrict__ out)
{
    __shared__ __align__(16) unsigned short wlds[8 * 12 * 64 * 8];   // 96 KB A-frags
    __shared__ __align__(16) unsigned short xfS[4 * 4 * 64 * 8];     // 16 KB x B-frags (single)
    __shared__ __align__(16) unsigned short hf[2 * 4 * 64 * 8];      // 8 KB own-h B-frags (dbuf)
    __shared__ int   labv[SEQG];
    __shared__ int   ready_s;
    __shared__ int   fast_s;

    const int tid = threadIdx.x;
    const int w   = tid >> 6;
    const int l   = tid & 63;
    const int lq  = l >> 4;
    const int ls  = l & 15;
    const int jj  = w >> 2;        // row half (0/1)
    const int cg  = w & 3;         // col group (16 seqs)
    const int grp = blockIdx.x & (NGRP - 1);
    const int m   = blockIdx.x >> 5;
    const int n0  = grp * SEQG;

    int* const flagBase = flags + grp * FLG_STRIDE;
    int* const xcdBase  = flags + XCD_OFF + grp * FLG_STRIDE;

    int maxlen = lengths[n0 + l];
#pragma unroll
    for (int s = 1; s < 64; s <<= 1) maxlen = max(maxlen, __shfl_xor(maxlen, s, 64));
    const int len_s = lengths[n0 + cg * 16 + ls];

    if (tid < SEQG) labv[tid] = labels[n0 + tid];
    if (tid == 0) { ready_s = 0; fast_s = 0; }

    // biases in registers (per-lane: gate rows for this wave's acc slots)
    f32x4 biasv[4];
#pragma unroll
    for (int g = 0; g < 4; ++g)
#pragma unroll
        for (int r = 0; r < 4; ++r) {
            int row = 256 * g + 32 * m + 16 * jj + 4 * lq + r;
            biasv[g][r] = bih[row] + bhh[row];
        }

    // publish this member's XCD id early (SYSTEM; own padded line; consumers
    // poll the value itself -> self-synchronizing, no ordering assumption)
    {
        unsigned xcc;
        asm volatile("s_getreg_b32 %0, hwreg(HW_REG_XCC_ID)" : "=s"(xcc));
        if (tid == 0)
            __hip_atomic_store(&xcdBase[m], (int)(xcc + 1),
                               __ATOMIC_RELAXED, __HIP_MEMORY_SCOPE_SYSTEM);
    }

    // ---- one-time: this member's A-frags (8 mt x 12 kt) -> LDS ----
    for (int idx = tid; idx < 8 * 12 * 64; idx += NT) {
        int mtl = idx / 768;
        int rem = idx - mtl * 768;
        int kt = rem >> 6, l2 = rem & 63;
        int g = mtl >> 1, j2 = mtl & 1;
        int gmt = 16 * g + 2 * m + j2;
        *(uint4*)&wlds[(size_t)idx * 8] =
            *(const uint4*)(wsA + ((size_t)(gmt * NKT + kt) * 64 + l2) * 8);
    }

    // x staging map: thread -> (seq, 16-dim octet)
    const int xs_s   = tid & 63;
    const int xs_oct = tid >> 6;

    auto stageX = [&](const f32x4* xv) {
#pragma unroll
        for (int dc = 0; dc < 4; ++dc) {
            int d0 = 16 * xs_oct + 4 * dc;
            int kt = d0 >> 5, cgs = xs_s >> 4;
            int lanep = (xs_s & 15) + 16 * ((d0 >> 3) & 3);
            uint2 pk;
            pk.x = f2bf(xv[dc][0]) | ((unsigned)f2bf(xv[dc][1]) << 16);
            pk.y = f2bf(xv[dc][2]) | ((unsigned)f2bf(xv[dc][3]) << 16);
            *(uint2*)&xfS[(size_t)((kt * 4 + cgs) * 64 + lanep) * 8 + (d0 & 4)] = pk;
        }
    };

    // stage x(0)
    {
        int tok = tokens[(n0 + xs_s) * TT + 0];
        const float* er = emb + (size_t)tok * EE + 16 * xs_oct;
        f32x4 x0[4];
#pragma unroll
        for (int dc = 0; dc < 4; ++dc) x0[dc] = *(const f32x4*)(er + 4 * dc);
        stageX(x0);
    }

    // ---- mode decision (wave0): poll all 8 xcd ids until nonzero, check
    // unanimity, broadcast via LDS. SYSTEM-only; completes before any
    // flag/ghf store. ----
    if (w == 0) {
        int x;
        for (;;) {
            x = (l < NMEM)
                ? __hip_atomic_load(&xcdBase[l], __ATOMIC_RELAXED, __HIP_MEMORY_SCOPE_SYSTEM)
                : 1;
            if (__ballot(x != 0) == ~0ull) break;
            __builtin_amdgcn_s_sleep(2);
        }
        int x0 = __shfl(x, 0, 64);
        bool eq = (l >= NMEM) || (x == x0);
        if (l == 0) fast_s = (__ballot(eq) == ~0ull) ? 1 : 0;
    }
    __syncthreads();   // wlds + labv + x(0) staging + fast_s visible
    const bool fast = (fast_s != 0);

    // zero hf buf0 + ghf parity0 slice (h(0) = 0) — CHOSEN mode (purity)
    if (tid < 256) {
        uint4 z = {0, 0, 0, 0};
        *(uint4*)&hf[(size_t)tid * 8] = z;
        size_t base = ((size_t)((grp * NMEM + m) * 2 + 0) * 4) * 512 + (size_t)tid * 8;
        if (fast) { st8_f(&ghf[base], 0, 0);   st8_f(&ghf[base + 4], 0, 0); }
        else      { st8_sys(&ghf[base], 0, 0); st8_sys(&ghf[base + 4], 0, 0); }
    }
    __syncthreads();   // drains zero stores (all waves) before flag post
    if (tid == 0) {
        if (fast) stflag_f(&flagBase[m], 1);
        else      __hip_atomic_store(&flagBase[m], 1, __ATOMIC_RELAXED, __HIP_MEMORY_SCOPE_SYSTEM);
    }

    // relay wait: wave0 polls flags; other waves spin on LDS
    auto relay_wait = [&](int need, bool fm) {
        if (w == 0) {
            int f;
            do {
                f = 0x7fffffff;
                if (l < NMEM)
                    f = fm ? ldflag_f(&flagBase[l])
                           : __hip_atomic_load(&flagBase[l], __ATOMIC_RELAXED, __HIP_MEMORY_SCOPE_SYSTEM);
                f = min(f, __shfl_xor(f, 1, 64));
                f = min(f, __shfl_xor(f, 2, 64));
                f = min(f, __shfl_xor(f, 4, 64));
                f = __shfl(f, 0, 64);
                if (f < need && !fm) __builtin_amdgcn_s_sleep(2);
            } while (f < need);
            __hip_atomic_store(&ready_s, need, __ATOMIC_RELEASE, __HIP_MEMORY_SCOPE_WORKGROUP);
        } else {
            while (__hip_atomic_load(&ready_s, __ATOMIC_ACQUIRE, __HIP_MEMORY_SCOPE_WORKGROUP) < need)
                __builtin_amdgcn_s_sleep(1);
        }
    };

    // prefetch x(1)
    f32x4 xv[4];
    if (maxlen > 1) {
        int tok = tokens[(n0 + xs_s) * TT + 1];
        const float* er = emb + (size_t)tok * EE + 16 * xs_oct;
#pragma unroll
        for (int dc = 0; dc < 4; ++dc) xv[dc] = *(const f32x4*)(er + 4 * dc);
    }

    // acc = bias + xpart(x(0))
    f32x4 acc[4], accN[4];
#pragma unroll
    for (int g = 0; g < 4; ++g) acc[g] = biasv[g];
#pragma unroll
    for (int kt = 0; kt < 4; ++kt) {
        const bf16x8 bx = *(const bf16x8*)&xfS[(size_t)((kt * 4 + cg) * 64 + l) * 8];
#pragma unroll
        for (int g = 0; g < 4; ++g)
            acc[g] = __builtin_amdgcn_mfma_f32_16x16x32_bf16(
                *(const bf16x8*)&wlds[(size_t)(((2 * g + jj) * 12 + kt) * 64 + l) * 8],
                bx, acc[g], 0, 0, 0);
    }
    __syncthreads();   // xfS reads done; iter 0 may restage

    float c_reg[4], h_reg[4];
#pragma unroll
    for (int r = 0; r < 4; ++r) { c_reg[r] = 0.0f; h_reg[r] = 0.0f; }

    // h publish mapping: unit u = 16*jj + 4*lq + r in member's 32-k tile
    const int u8      = 2 * jj + (lq >> 1);
    const int lanep_h = 16 * u8 + ls;
    const int joff_h  = 4 * (lq & 1);
    const size_t gb0  = ((size_t)((grp * NMEM + m) * 2 + 0) * 4 + cg) * 512 + (size_t)lanep_h * 8 + joff_h;
    const size_t gb1  = gb0 + 4 * 512;

    // ---- recurrence (steady state: xpart(t) already in acc) ----
    for (int t = 0; t < maxlen; ++t) {
        const int cur = t & 1, nxt = cur ^ 1;
        const bool doX = (t + 1 < maxlen);

        // head: stage x(t+1) from regs (partner-independent)
        if (doX) stageX(xv);
        // own-h B-frag (hf[cur] written before last barrier)
        const bf16x8 bo = *(const bf16x8*)&hf[(size_t)((cur * 4 + cg) * 64 + l) * 8];
        if (doX) __syncthreads();   // staging visible; cheap (no vmem pending)

        // prefetch x(t+2) (drained well before use)
        if (t + 2 < maxlen) {
            int tok = tokens[(n0 + xs_s) * TT + t + 2];
            const float* er = emb + (size_t)tok * EE + 16 * xs_oct;
#pragma unroll
            for (int dc = 0; dc < 4; ++dc) xv[dc] = *(const f32x4*)(er + 4 * dc);
        }

        // xpart(t+1) into accN — fills the wait window
        if (doX) {
#pragma unroll
            for (int g = 0; g < 4; ++g) accN[g] = biasv[g];
#pragma unroll
            for (int kt = 0; kt < 4; ++kt) {
                const bf16x8 bx = *(const bf16x8*)&xfS[(size_t)((kt * 4 + cg) * 64 + l) * 8];
#pragma unroll
                for (int g = 0; g < 4; ++g)
                    accN[g] = __builtin_amdgcn_mfma_f32_16x16x32_bf16(
                        *(const bf16x8*)&wlds[(size_t)(((2 * g + jj) * 12 + kt) * 64 + l) * 8],
                        bx, accN[g], 0, 0, 0);
            }
        }

        // wait for all members' h(t)
        relay_wait(t + 1, fast);

        // partner B-frag loads
        bf16x8 bp[7];
        if (fast) {
            const unsigned short* pa[7];
#pragma unroll
            for (int i = 0; i < 7; ++i) {
                int p = i + (i >= m ? 1 : 0);
                size_t b = ((size_t)((grp * NMEM + p) * 2 + cur) * 4 + cg) * 512;
                pa[i] = &ghf[b + (size_t)l * 8];
            }
            // individually-issued sc0 loads (pipeline in the XCD L2), one
            // drain, then a full sched_barrier so no MFMA consumes the
            // destinations before the waitcnt (rule #18).
            union { u32x4 q; bf16x8 v; } u0, u1, u2, u3, u4, u5, u6;
            asm volatile("global_load_dwordx4 %0, %1, off sc0" : "=v"(u0.q) : "v"(pa[0]) : "memory");
            asm volatile("global_load_dwordx4 %0, %1, off sc0" : "=v"(u1.q) : "v"(pa[1]) : "memory");
            asm volatile("global_load_dwordx4 %0, %1, off sc0" : "=v"(u2.q) : "v"(pa[2]) : "memory");
            asm volatile("global_load_dwordx4 %0, %1, off sc0" : "=v"(u3.q) : "v"(pa[3]) : "memory");
            asm volatile("global_load_dwordx4 %0, %1, off sc0" : "=v"(u4.q) : "v"(pa[4]) : "memory");
            asm volatile("global_load_dwordx4 %0, %1, off sc0" : "=v"(u5.q) : "v"(pa[5]) : "memory");
            asm volatile("global_load_dwordx4 %0, %1, off sc0" : "=v"(u6.q) : "v"(pa[6]) : "memory");
            asm volatile("s_waitcnt vmcnt(0)" ::: "memory");
            __builtin_amdgcn_sched_barrier(0);
            bp[0] = u0.v; bp[1] = u1.v; bp[2] = u2.v; bp[3] = u3.v;
            bp[4] = u4.v; bp[5] = u5.v; bp[6] = u6.v;
        } else {
#pragma unroll
            for (int i = 0; i < 7; ++i) {
                int p = i + (i >= m ? 1 : 0);
                size_t b = ((size_t)((grp * NMEM + p) * 2 + cur) * 4 + cg) * 512;
                bp[i] = ld16_sys(&ghf[b + (size_t)l * 8]);
            }
        }

        // own-h part first (hides partner-load latency)
#pragma unroll
        for (int g = 0; g < 4; ++g)
            acc[g] = __builtin_amdgcn_mfma_f32_16x16x32_bf16(
                *(const bf16x8*)&wlds[(size_t)(((2 * g + jj) * 12 + 4 + m) * 64 + l) * 8],
                bo, acc[g], 0, 0, 0);
        // partner-h parts
#pragma unroll
        for (int i = 0; i < 7; ++i) {
            int p = i + (i >= m ? 1 : 0);
            int kt = 4 + p;
#pragma unroll
            for (int g = 0; g < 4; ++g)
                acc[g] = __builtin_amdgcn_mfma_f32_16x16x32_bf16(
                    *(const bf16x8*)&wlds[(size_t)(((2 * g + jj) * 12 + kt) * 64 + l) * 8],
                    bp[i], acc[g], 0, 0, 0);
        }

        // in-register cell update
        const bool live = (t < len_s);
#pragma unroll
        for (int r = 0; r < 4; ++r) {
            if (live) {
                float ig = sigf(acc[0][r]);
                float fg = sigf(acc[1][r]);
                float gg = tanh_fast(acc[2][r]);
                float og = sigf(acc[3][r]);
                float cc = fg * c_reg[r] + ig * gg;
                c_reg[r] = cc;
                h_reg[r] = og * tanh_fast(cc);
            }
        }

        // carry pipelined xpart
        if (doX) {
#pragma unroll
            for (int g = 0; g < 4; ++g) acc[g] = accN[g];
        }

        // publish h(t+1): LDS nxt + ghf store, parity (t+1)&1
        {
            uint2 hp;
            hp.x = f2bf(h_reg[0]) | ((unsigned)f2bf(h_reg[1]) << 16);
            hp.y = f2bf(h_reg[2]) | ((unsigned)f2bf(h_reg[3]) << 16);
            *(uint2*)&hf[(size_t)((nxt * 4 + cg) * 64 + lanep_h) * 8 + joff_h] = hp;
            unsigned short* gp = &ghf[((t + 1) & 1) ? gb1 : gb0];
            if (fast) st8_f(gp, hp.x, hp.y);
            else      st8_sys(gp, hp.x, hp.y);
        }

        __syncthreads();   // barrier B: drains ghf stores (L2 coherence point)
        if (tid == 0) {
            if (fast) stflag_f(&flagBase[m], t + 2);
            else      __hip_atomic_store(&flagBase[m], t + 2, __ATOMIC_RELAXED, __HIP_MEMORY_SCOPE_SYSTEM);
        }
    }

    // ---- epilogue 1: embeds = mean(c_f) for own 32 units ----
#pragma unroll
    for (int r = 0; r < 4; ++r) {
        float v = c_reg[r];
        v += __shfl_xor(v, 1, 64);
        v += __shfl_xor(v, 2, 64);
        v += __shfl_xor(v, 4, 64);
        v += __shfl_xor(v, 8, 64);
        if (ls == 0)
            atomicAdd(&out[32 * m + 16 * jj + 4 * lq + r], v * (1.0f / NSEQ));
    }

    // ---- epilogue 2 (member 0): logits GEMM + log-softmax ----
    if (m == 0) {
        relay_wait(maxlen + 1, fast);
        const int fin = maxlen & 1;
        float* lg = (float*)wlds;            // reuse: 16 seqs x 1024 logits
        float lossAcc = 0.0f;

        for (int cgo = 0; cgo < 4; ++cgo) {
            bf16x8 bq[8];
#pragma unroll
            for (int p = 0; p < 8; ++p) {
                size_t b = ((size_t)((grp * NMEM + p) * 2 + fin) * 4 + cgo) * 512;
                const unsigned short* ptr = &ghf[b + (size_t)l * 8];
                bq[p] = fast ? ld16_f(ptr) : ld16_sys(ptr);
            }
            __syncthreads();
#pragma unroll
            for (int i = 0; i < 8; ++i) {
                int mt = 8 * w + i;
                f32x4 a = {0.0f, 0.0f, 0.0f, 0.0f};
#pragma unroll
                for (int p = 0; p < 8; ++p)
                    a = __builtin_amdgcn_mfma_f32_16x16x32_bf16(
                        *(const bf16x8*)(wsO + ((size_t)(mt * NKT_O + p) * 64 + l) * 8),
                        bq[p], a, 0, 0, 0);
#pragma unroll
                for (int r = 0; r < 4; ++r) {
                    int cls = 16 * mt + 4 * lq + r;
                    lg[(size_t)ls * 1024 + cls] = (cls < LL) ? (a[r] + bout[cls]) : -INFINITY;
                }
            }
            __syncthreads();
            const int s2 = tid >> 5;
            const int i2 = tid & 31;
            const float* row = &lg[(size_t)s2 * 1024];
            float mx = -INFINITY;
#pragma unroll
            for (int k = 0; k < 32; ++k) mx = fmaxf(mx, row[i2 + 32 * k]);
            mx = fmaxf(mx, __shfl_xor(mx, 1, 64));
            mx = fmaxf(mx, __shfl_xor(mx, 2, 64));
            mx = fmaxf(mx, __shfl_xor(mx, 4, 64));
            mx = fmaxf(mx, __shfl_xor(mx, 8, 64));
            mx = fmaxf(mx, __shfl_xor(mx, 16, 64));
            float sm = 0.0f;
#pragma unroll
            for (int k = 0; k < 32; ++k) sm += __expf(row[i2 + 32 * k] - mx);
            sm += __shfl_xor(sm, 1, 64);
            sm += __shfl_xor(sm, 2, 64);
            sm += __shfl_xor(sm, 4, 64);
            sm += __shfl_xor(sm, 8, 64);
            sm += __shfl_xor(sm, 16, 64);
            if (i2 == 0) {
                int lab = labv[cgo * 16 + s2];
                float lp = row[lab] - mx - __logf(sm);
                lossAcc += -lp;
            }
        }
        if ((tid & 31) == 0)
            atomicAdd(&out[HH], lossAcc * (1.0f / NSEQ));
    }
}

extern "C" void kernel_launch(void* const* d_in, const int* in_sizes, int n_in,
                              void* d_out, int out_size, void* d_ws, size_t ws_size,
                              hipStream_t stream)
{
    const int*   tokens  = (const int*)d_in[0];
    const int*   lengths = (const int*)d_in[1];
    const int*   labels  = (const int*)d_in[2];
    const float* emb     = (const float*)d_in[3];
    const float* Wih     = (const float*)d_in[4];
    const float* Whh     = (const float*)d_in[5];
    const float* bih     = (const float*)d_in[6];
    const float* bhh     = (const float*)d_in[7];
    const float* Wout    = (const float*)d_in[8];
    const float* bout    = (const float*)d_in[9];
    float* out = (float*)d_out;

    unsigned short* wsA  = (unsigned short*)d_ws;
    unsigned short* wsO  = wsA + WSA_ELEMS;
    unsigned short* ghf  = wsO + WSO_ELEMS;
    int*            flg  = (int*)(ghf + GHF_SHORTS);

    hipLaunchKernelGGL(init_out_kernel, dim3(4), dim3(512), 0, stream, out, flg);
    {
        int nthr = NMT * NKT * 64 + NMT * NKT_O * 64;
        hipLaunchKernelGGL(convert_weights, dim3((nthr + 255) / 256), dim3(256), 0, stream,
                           Wih, Whh, Wout, wsA, wsO);
    }
    hipLaunchKernelGGL(lstm_group_kernel, dim3(NGRP * NMEM), dim3(NT), 0, stream,
                       tokens, lengths, labels, emb, bih, bhh, bout, wsA, wsO, ghf, flg, out);
}